// Round 2
// baseline (210.493 us; speedup 1.0000x reference)
//
#include <hip/hip_runtime.h>
#include <math.h>

#define NA   21
#define NM   64
#define ND   210
#define DK   216          // padded K for stage1 (rows 210..215 zero)
#define NT   8192
#define KS   128          // stage2 K-splits (64 t each)

#define QC 0.22360679774997896f   // sqrt(5)/10
#define KE 0.016666666666666666f  // 5/(3*sig^2)

// ---- workspace layout (float offsets) ----
#define O_QXST 0u                          // [DK][64] (alloc 16384)
#define O_QXTT 16384u                      // [DK][NT]  1769472
#define O_JXT  (O_QXTT + 1769472u)         // [DK][NT]  1769472
#define O_NT   (O_JXT + 1769472u)          // [NT]
#define O_CJ   (O_NT + 8192u)              // [NT]
#define O_NX   (O_CJ + 8192u)              // [64]
#define O_ES   (O_NX + 64u)                // [64]
#define O_WA   (O_ES + 64u)                // [64]
#define O_AB   (O_WA + 64u)                // [2][64][256] (atomic fallback)
#define O_W1   (O_AB + 32768u)             // [NT][64]
#define O_E1   (O_W1 + 524288u)            // [NT][64]
#define O_PB   (O_E1 + 524288u)            // [KS][2][64][256]
#define END_PB (O_PB + (unsigned)KS * 32768u)
#define END_AT O_PB

__device__ __forceinline__ void d_to_ij(int d, int& i, int& j) {
    int ii = (int)((1.0f + sqrtf(1.0f + 8.0f * (float)d)) * 0.5f);
    while (ii * (ii - 1) / 2 > d) --ii;
    while ((ii + 1) * ii / 2 <= d) ++ii;
    i = ii;
    j = d - ii * (ii - 1) / 2;
}

__global__ void k_zero(float* __restrict__ p, int n) {
    int i = blockIdx.x * 256 + threadIdx.x;
    if (i < n) p[i] = 0.0f;
}

// grid 64 (m) x 256: qxsT[d][m] = q/dist(pair d), rows 210..215 zero; nx[m]
__global__ void k_geom(const float* __restrict__ Rs, float* __restrict__ qxsT,
                       float* __restrict__ nx) {
    int m = blockIdx.x, tid = threadIdx.x;
    __shared__ float R[NA * 3];
    __shared__ float red[256];
    if (tid < NA * 3) R[tid] = Rs[m * NA * 3 + tid];
    __syncthreads();
    float local = 0.0f;
    for (int d = tid; d < DK; d += 256) {
        float v = 0.0f;
        if (d < ND) {
            int i, j; d_to_ij(d, i, j);
            float dx = R[i * 3] - R[j * 3];
            float dy = R[i * 3 + 1] - R[j * 3 + 1];
            float dz = R[i * 3 + 2] - R[j * 3 + 2];
            v = QC / sqrtf(dx * dx + dy * dy + dz * dz);
        }
        qxsT[d * NM + m] = v;
        local += v * v;
    }
    red[tid] = local;
    __syncthreads();
    for (int s = 128; s > 0; s >>= 1) {
        if (tid < s) red[tid] += red[tid + s];
        __syncthreads();
    }
    if (tid == 0) nx[m] = red[0];
}

// grid 128 (t-tiles of 64) x 256: dst[d][t] = scale*src[t][d], rows d in [210,216) zero
__global__ void k_transpose(const float* __restrict__ src, float* __restrict__ dst,
                            float scale) {
    int t0 = blockIdx.x * 64, tid = threadIdx.x;
    __shared__ float tile[64][ND + 1];
    for (int idx = tid; idx < 64 * ND; idx += 256) {
        int t = idx / ND, d = idx - t * ND;
        tile[t][d] = src[(size_t)(t0 + t) * ND + d];
    }
    __syncthreads();
    for (int idx = tid; idx < DK * 64; idx += 256) {
        int d = idx >> 6, t = idx & 63;
        float v = (d < ND) ? scale * tile[t][d] : 0.0f;
        dst[(size_t)d * NT + t0 + t] = v;
    }
}

// grid 2048 x 256 (wave per t): nt[t] = ||q xt||^2, cJ[t] = (q xt).Jx  (reads originals)
__global__ void k_rowstats(const float* __restrict__ xs, const float* __restrict__ Jx,
                           float* __restrict__ nt, float* __restrict__ cJ) {
    int t = blockIdx.x * 4 + (threadIdx.x >> 6);
    int lane = threadIdx.x & 63;
    const float* xr = xs + (size_t)t * ND;
    const float* jr = Jx + (size_t)t * ND;
    float sn = 0.0f, sc = 0.0f;
    for (int c = lane; c < ND; c += 64) {
        float x = xr[c], j = jr[c];
        sn = fmaf(x, x, sn);
        sc = fmaf(x, j, sc);
    }
#pragma unroll
    for (int off = 32; off > 0; off >>= 1) {
        sn += __shfl_xor(sn, off);
        sc += __shfl_xor(sc, off);
    }
    if (lane == 0) {
        nt[t] = QC * QC * sn;
        cJ[t] = QC * sc;
    }
}

// Stage 1: grid 256 (t-tiles of 32) x 256 thr. Tile 64m x 32t, thread 2m x 4t.
// A (qxs, 216x64) fully preloaded in LDS; barrier-free K-loop with broadcast B loads.
__global__ __launch_bounds__(256) void k_stage1(
    const float* __restrict__ qxsT, const float* __restrict__ qxtT,
    const float* __restrict__ JxT, const float* __restrict__ nt,
    const float* __restrict__ cJ, const float* __restrict__ nx,
    float* __restrict__ w1T, float* __restrict__ e1T,
    float* __restrict__ EsAcc, float* __restrict__ Wacc) {
    const int t0 = blockIdx.x * 32;
    const int tid = threadIdx.x;
    const int mloc = (tid & 31) * 2;   // m base: lanes 0..31 -> m 0..62
    const int tloc = (tid >> 5) * 4;   // t base within tile
    __shared__ float Alds[DK * 64];    // 55296 B
    __shared__ float red[64][9];

    for (int i = tid; i < DK * 16; i += 256)
        ((float4*)Alds)[i] = ((const float4*)qxsT)[i];
    __syncthreads();

    float c1[2][4] = {};
    float c2[2][4] = {};
    const float* bp1 = qxtT + t0 + tloc;
    const float* bp2 = JxT + t0 + tloc;

#pragma unroll 8
    for (int d = 0; d < DK; ++d) {
        const float2 a = *(const float2*)&Alds[d * 64 + mloc];
        const float4 b1 = *(const float4*)&bp1[(size_t)d * NT];
        const float4 b2 = *(const float4*)&bp2[(size_t)d * NT];
        float bb1[4] = {b1.x, b1.y, b1.z, b1.w};
        float bb2[4] = {b2.x, b2.y, b2.z, b2.w};
#pragma unroll
        for (int j = 0; j < 4; ++j) {
            c1[0][j] = fmaf(a.x, bb1[j], c1[0][j]);
            c1[1][j] = fmaf(a.y, bb1[j], c1[1][j]);
            c2[0][j] = fmaf(a.x, bb2[j], c2[0][j]);
            c2[1][j] = fmaf(a.y, bb2[j], c2[1][j]);
        }
    }

    // epilogue: exp / softening, store w1T/e1T (t-major, coalesced), Es/W partials
    const float nx0 = nx[mloc], nx1 = nx[mloc + 1];
    float esl[2] = {0.0f, 0.0f}, wl[2] = {0.0f, 0.0f};
#pragma unroll
    for (int j = 0; j < 4; ++j) {
        const int t = t0 + tloc + j;
        const float ntv = nt[t], cjv = cJ[t];
        float wv[2], ev[2];
#pragma unroll
        for (int i = 0; i < 2; ++i) {
            float sq = (i ? nx1 : nx0) - 2.0f * c1[i][j] + ntv;
            float xd = sqrtf(fmaxf(sq, 0.0f));
            float e = KE * expf(-xd);
            float dotv = c2[i][j] - cjv;
            wv[i] = e * dotv;
            ev[i] = e * (1.0f + xd);
            esl[i] += ev[i] * dotv;
            wl[i] += wv[i];
        }
        *(float2*)&w1T[(size_t)t * 64 + mloc] = make_float2(wv[0], wv[1]);
        *(float2*)&e1T[(size_t)t * 64 + mloc] = make_float2(ev[0], ev[1]);
    }
    const int tg = tid >> 5;
    red[mloc][tg] = esl[0];
    red[mloc + 1][tg] = esl[1];
    __syncthreads();
    if (tid < 64) {
        float s = 0.0f;
#pragma unroll
        for (int k = 0; k < 8; ++k) s += red[tid][k];
        atomicAdd(&EsAcc[tid], s);
    }
    __syncthreads();
    red[mloc][tg] = wl[0];
    red[mloc + 1][tg] = wl[1];
    __syncthreads();
    if (tid < 64) {
        float s = 0.0f;
#pragma unroll
        for (int k = 0; k < 8; ++k) s += red[tid][k];
        atomicAdd(&Wacc[tid], s);
    }
}

// Stage 2: grid (4 d-tiles, KS) x 256. lane=m, wave owns 16 d's in registers.
// Barrier-free K-loop (64 t), B broadcast straight from original row-major arrays.
template <bool PBUF>
__global__ __launch_bounds__(256) void k_stage2(
    const float* __restrict__ w1T, const float* __restrict__ e1T,
    const float* __restrict__ xs, const float* __restrict__ Jx,
    float* __restrict__ outp) {  // PBUF ? Pbuf : ABacc
    const int d0 = blockIdx.x * 64;
    const int ks = blockIdx.y;
    const int kt0 = ks * (NT / KS);
    const int lane = threadIdx.x & 63;
    const int w = threadIdx.x >> 6;
    const int dw = d0 + w * 16;

    float accA[16] = {};
    float accB[16] = {};

#pragma unroll 2
    for (int t = kt0; t < kt0 + NT / KS; ++t) {
        const float aw = w1T[(size_t)t * 64 + lane] * QC;
        const float ae = e1T[(size_t)t * 64 + lane];
        const float* xr = xs + (size_t)t * ND + dw;
        const float* jr = Jx + (size_t)t * ND + dw;
        float b1[16], b2[16];
#pragma unroll
        for (int g = 0; g < 8; ++g) {
            const int db = dw + g * 2;
            if (db + 1 < ND) {  // float2-aligned always (t*210 even, dw even)
                const float2 p1 = *(const float2*)&xr[g * 2];
                const float2 p2 = *(const float2*)&jr[g * 2];
                b1[g * 2] = p1.x; b1[g * 2 + 1] = p1.y;
                b2[g * 2] = p2.x; b2[g * 2 + 1] = p2.y;
            } else {
                b1[g * 2] = (db < ND) ? xr[g * 2] : 0.0f;
                b2[g * 2] = (db < ND) ? jr[g * 2] : 0.0f;
                b1[g * 2 + 1] = 0.0f;
                b2[g * 2 + 1] = 0.0f;
            }
        }
#pragma unroll
        for (int i = 0; i < 16; ++i) {
            accA[i] = fmaf(aw, b1[i], accA[i]);
            accB[i] = fmaf(ae, b2[i], accB[i]);
        }
    }

    // repack through LDS (odd row pad -> conflict-free), then coalesced output
    __shared__ float tile[2 * 64 * 65];
#pragma unroll
    for (int i = 0; i < 16; ++i) {
        tile[lane * 65 + w * 16 + i] = accA[i];
        tile[(64 + lane) * 65 + w * 16 + i] = accB[i];
    }
    __syncthreads();
    for (int f = threadIdx.x; f < 2048; f += 256) {
        const int mat = f >> 10, r = (f >> 4) & 63, c = (f & 15) * 4;
        const int base = (mat * 64 + r) * 65 + c;
        const size_t o = (size_t)mat * 16384 + (size_t)r * 256 + d0 + c;
        if (PBUF) {
            float4 v = make_float4(tile[base], tile[base + 1], tile[base + 2], tile[base + 3]);
            *(float4*)&outp[(size_t)ks * 32768 + o] = v;
        } else {
            atomicAdd(&outp[o], tile[base]);
            atomicAdd(&outp[o + 1], tile[base + 1]);
            atomicAdd(&outp[o + 2], tile[base + 2]);
            atomicAdd(&outp[o + 3], tile[base + 3]);
        }
    }
}

// grid 64 (m) x 256: fused partial-reduce (nparts) + expand_tril + force contraction + Es
__global__ void k_final(const float* __restrict__ Rs, const float* __restrict__ qxsT,
                        const float* __restrict__ P, int nparts,
                        const float* __restrict__ EsAcc, const float* __restrict__ Wacc,
                        float* __restrict__ out) {
    int m = blockIdx.x, tid = threadIdx.x;
    __shared__ float R[NA * 3];
    __shared__ float Ff[NA][NA];
    if (tid < NA * 3) R[tid] = Rs[m * NA * 3 + tid];
    if (tid < NA) Ff[tid][tid] = 0.0f;
    __syncthreads();
    if (tid < ND) {
        float s1a = 0.0f, s1b = 0.0f, s2a = 0.0f, s2b = 0.0f;
        const size_t base = (size_t)m * 256 + tid;
        int k = 0;
        for (; k + 1 < nparts; k += 2) {
            s1a += P[(size_t)k * 32768 + base];
            s1b += P[(size_t)(k + 1) * 32768 + base];
            s2a += P[(size_t)k * 32768 + 16384 + base];
            s2b += P[(size_t)(k + 1) * 32768 + 16384 + base];
        }
        for (; k < nparts; ++k) {
            s1a += P[(size_t)k * 32768 + base];
            s2a += P[(size_t)k * 32768 + 16384 + base];
        }
        int i, j; d_to_ij(tid, i, j);
        float dx = R[i * 3] - R[j * 3];
        float dy = R[i * 3 + 1] - R[j * 3 + 1];
        float dz = R[i * 3 + 2] - R[j * 3 + 2];
        float dist2 = dx * dx + dy * dy + dz * dz;
        float fsx = qxsT[tid * NM + m] * Wacc[m] - (s1a + s1b) - (s2a + s2b);
        float f = fsx / (dist2 * sqrtf(dist2));
        Ff[i][j] = f;
        Ff[j][i] = f;
    }
    __syncthreads();
    if (tid < NA * 3) {
        int a = tid / 3, c = tid % 3;
        float s = 0.0f;
        for (int b = 0; b < NA; ++b) {
            if (b == a) continue;
            s += Ff[a][b] * (R[a * 3 + c] - R[b * 3 + c]);
        }
        out[NM + m * NA * 3 + tid] = s;
    }
    if (tid == 0) out[m] = EsAcc[m] / QC;
}

extern "C" void kernel_launch(void* const* d_in, const int* in_sizes, int n_in,
                              void* d_out, int out_size, void* d_ws, size_t ws_size,
                              hipStream_t stream) {
    const float* Rs = (const float*)d_in[0];
    const float* xs_train = (const float*)d_in[1];
    const float* Jx_alphas = (const float*)d_in[2];
    float* out = (float*)d_out;
    float* ws = (float*)d_ws;

    float* qxsT = ws + O_QXST;
    float* qxtT = ws + O_QXTT;
    float* JxT  = ws + O_JXT;
    float* nt   = ws + O_NT;
    float* cJ   = ws + O_CJ;
    float* nx   = ws + O_NX;
    float* EsAcc = ws + O_ES;
    float* Wacc  = ws + O_WA;
    float* ABacc = ws + O_AB;
    float* w1T  = ws + O_W1;
    float* e1T  = ws + O_E1;
    float* Pbuf = ws + O_PB;

    const bool use_pbuf = ws_size >= (size_t)END_PB * sizeof(float);
    const int nzero = use_pbuf ? 128 : (128 + 32768);  // Es+Wa [+AB]

    k_zero<<<(nzero + 255) / 256, 256, 0, stream>>>(EsAcc, nzero);
    k_geom<<<NM, 256, 0, stream>>>(Rs, qxsT, nx);
    k_transpose<<<NT / 64, 256, 0, stream>>>(xs_train, qxtT, QC);
    k_transpose<<<NT / 64, 256, 0, stream>>>(Jx_alphas, JxT, 1.0f);
    k_rowstats<<<NT / 4, 256, 0, stream>>>(xs_train, Jx_alphas, nt, cJ);
    k_stage1<<<NT / 32, 256, 0, stream>>>(qxsT, qxtT, JxT, nt, cJ, nx, w1T, e1T, EsAcc, Wacc);
    if (use_pbuf) {
        k_stage2<true><<<dim3(4, KS), 256, 0, stream>>>(w1T, e1T, xs_train, Jx_alphas, Pbuf);
        k_final<<<NM, 256, 0, stream>>>(Rs, qxsT, Pbuf, KS, EsAcc, Wacc, out);
    } else {
        k_stage2<false><<<dim3(4, KS), 256, 0, stream>>>(w1T, e1T, xs_train, Jx_alphas, ABacc);
        k_final<<<NM, 256, 0, stream>>>(Rs, qxsT, ABacc, 1, EsAcc, Wacc, out);
    }
}

// Round 3
// 179.981 us; speedup vs baseline: 1.1695x; 1.1695x over previous
//
#include <hip/hip_runtime.h>
#include <math.h>

#define NA   21
#define NM   64
#define ND   210
#define DP   224          // padded descriptor row (d 210..223 zero)
#define DG   53           // 4-wide d-groups covering 0..211 (rows 210+ zero)
#define NT   8192
#define KS   128          // stage2 K-splits (64 t each)

#define QC 0.22360679774997896f   // sqrt(5)/10
#define KE 0.016666666666666666f  // 5/(3*sig^2)

// ---- workspace layout (float offsets) ----
#define O_XP   0u                        // [NT][DP]      1835008
#define O_JP   1835008u                  // [NT][DP]      1835008
#define O_W1   3670016u                  // [NT][64]      524288
#define O_E1   4194304u                  // [NT][64]      524288
#define O_QXST 4718592u                  // [216][64]     13824
#define O_NT   4732416u                  // [NT]          8192
#define O_CJ   4740608u                  // [NT]          8192
#define O_NX   4748800u                  // [64]
#define O_ES   4748864u                  // [64]
#define O_WA   4748928u                  // [64]
#define O_AB   4748992u                  // [2][64][DP]   28672
#define O_PB   4777664u                  // [KS][2][64][DP] 3670016
#define END_PB 8447680u                  // 33.8 MB
#define NZERO  (64 + 64 + 28672)         // ES+WA+AB contiguous

__device__ __forceinline__ void d_to_ij(int d, int& i, int& j) {
    int ii = (int)((1.0f + sqrtf(1.0f + 8.0f * (float)d)) * 0.5f);
    while (ii * (ii - 1) / 2 > d) --ii;
    while ((ii + 1) * ii / 2 <= d) ++ii;
    i = ii;
    j = d - ii * (ii - 1) / 2;
}

__global__ void k_zero(float* __restrict__ p, int n) {
    int i = blockIdx.x * 256 + threadIdx.x;
    if (i < n) p[i] = 0.0f;
}

// grid 64 (m) x 256: qxsT[d][m] = q/dist(pair d), rows 210..215 zero; nx[m]
__global__ void k_geom(const float* __restrict__ Rs, float* __restrict__ qxsT,
                       float* __restrict__ nx) {
    int m = blockIdx.x, tid = threadIdx.x;
    __shared__ float R[NA * 3];
    __shared__ float red[256];
    if (tid < NA * 3) R[tid] = Rs[m * NA * 3 + tid];
    __syncthreads();
    float local = 0.0f;
    for (int d = tid; d < 216; d += 256) {
        float v = 0.0f;
        if (d < ND) {
            int i, j; d_to_ij(d, i, j);
            float dx = R[i * 3] - R[j * 3];
            float dy = R[i * 3 + 1] - R[j * 3 + 1];
            float dz = R[i * 3 + 2] - R[j * 3 + 2];
            v = QC / sqrtf(dx * dx + dy * dy + dz * dz);
        }
        qxsT[d * NM + m] = v;
        local += v * v;
    }
    red[tid] = local;
    __syncthreads();
    for (int s = 128; s > 0; s >>= 1) {
        if (tid < s) red[tid] += red[tid + s];
        __syncthreads();
    }
    if (tid == 0) nx[m] = red[0];
}

// grid 14336 x 256: Xp[t][d] = QC*xs[t][d] (zero-pad d>=210); Jp = Jx padded
__global__ void k_pad(const float* __restrict__ xs, const float* __restrict__ Jx,
                      float* __restrict__ Xp, float* __restrict__ Jp) {
    int o = blockIdx.x * 256 + threadIdx.x;   // < 2*NT*DP
    int arr = o / (NT * DP);
    int r = o - arr * (NT * DP);
    int t = r / DP, d = r - t * DP;
    float v = 0.0f;
    if (d < ND) {
        v = arr ? Jx[t * ND + d] : QC * xs[t * ND + d];
    }
    (arr ? Jp : Xp)[r] = v;
}

// grid 2048 x 256 (wave per t): nt[t] = ||q xt||^2, cJ[t] = (q xt).Jx
__global__ void k_rowstats(const float* __restrict__ xs, const float* __restrict__ Jx,
                           float* __restrict__ nt, float* __restrict__ cJ) {
    int t = blockIdx.x * 4 + (threadIdx.x >> 6);
    int lane = threadIdx.x & 63;
    const float* xr = xs + (size_t)t * ND;
    const float* jr = Jx + (size_t)t * ND;
    float sn = 0.0f, sc = 0.0f;
    for (int c = lane; c < ND; c += 64) {
        float x = xr[c], j = jr[c];
        sn = fmaf(x, x, sn);
        sc = fmaf(x, j, sc);
    }
#pragma unroll
    for (int off = 32; off > 0; off >>= 1) {
        sn += __shfl_xor(sn, off);
        sc += __shfl_xor(sc, off);
    }
    if (lane == 0) {
        nt[t] = QC * QC * sn;
        cJ[t] = QC * sc;
    }
}

// Stage 1: grid 256 (t-strips of 32) x 256 thr. lane=m, wave=8t.
// A panel (216x64) in LDS; B rows broadcast float4 from padded Xp/Jp.
__global__ __launch_bounds__(256) void k_stage1(
    const float* __restrict__ qxsT, const float* __restrict__ Xp,
    const float* __restrict__ Jp, const float* __restrict__ nt,
    const float* __restrict__ cJ, const float* __restrict__ nx,
    float* __restrict__ w1T, float* __restrict__ e1T,
    float* __restrict__ EsAcc, float* __restrict__ Wacc) {
    const int tid = threadIdx.x;
    const int lane = tid & 63;          // m
    const int w = tid >> 6;
    const int tw = blockIdx.x * 32 + w * 8;
    __shared__ float A[216 * 64];       // 55296 B
    __shared__ float redE[4][64];
    __shared__ float redW[4][64];

    for (int i = tid; i < 216 * 16; i += 256)
        ((float4*)A)[i] = ((const float4*)qxsT)[i];
    __syncthreads();

    float c1[8] = {};
    float c2[8] = {};

    for (int g = 0; g < DG; ++g) {
        const int d0 = g * 4;
        const float a0 = A[(d0 + 0) * 64 + lane];
        const float a1 = A[(d0 + 1) * 64 + lane];
        const float a2 = A[(d0 + 2) * 64 + lane];
        const float a3 = A[(d0 + 3) * 64 + lane];
#pragma unroll
        for (int j = 0; j < 8; ++j) {
            const float4 bx = *(const float4*)&Xp[(size_t)(tw + j) * DP + d0];
            const float4 bj = *(const float4*)&Jp[(size_t)(tw + j) * DP + d0];
            c1[j] = fmaf(a0, bx.x, c1[j]);
            c1[j] = fmaf(a1, bx.y, c1[j]);
            c1[j] = fmaf(a2, bx.z, c1[j]);
            c1[j] = fmaf(a3, bx.w, c1[j]);
            c2[j] = fmaf(a0, bj.x, c2[j]);
            c2[j] = fmaf(a1, bj.y, c2[j]);
            c2[j] = fmaf(a2, bj.z, c2[j]);
            c2[j] = fmaf(a3, bj.w, c2[j]);
        }
    }

    const float nxm = nx[lane];
    float es = 0.0f, wsum = 0.0f;
#pragma unroll
    for (int j = 0; j < 8; ++j) {
        const int t = tw + j;
        float sq = fmaxf(nxm - 2.0f * c1[j] + nt[t], 0.0f);
        float xd = sqrtf(sq);
        float e = KE * expf(-xd);
        float dotv = c2[j] - cJ[t];
        float wv = e * dotv;
        float ev = e * (1.0f + xd);
        w1T[(size_t)t * 64 + lane] = wv;     // coalesced 256 B
        e1T[(size_t)t * 64 + lane] = ev;
        es += ev * dotv;
        wsum += wv;
    }
    redE[w][lane] = es;
    redW[w][lane] = wsum;
    __syncthreads();
    if (tid < 64) {
        atomicAdd(&EsAcc[tid], redE[0][tid] + redE[1][tid] + redE[2][tid] + redE[3][tid]);
        atomicAdd(&Wacc[tid], redW[0][tid] + redW[1][tid] + redW[2][tid] + redW[3][tid]);
    }
}

// Stage 2: grid (7 d-tiles of 32, KS) x 256. lane=m, wave=8d, K-chunk 64 t.
// A[m,d] = sum_t w1*qxt ; B[m,d] = sum_t e1*Jx. Barrier-free.
template <bool PBUF>
__global__ __launch_bounds__(256) void k_stage2(
    const float* __restrict__ w1T, const float* __restrict__ e1T,
    const float* __restrict__ Xp, const float* __restrict__ Jp,
    float* __restrict__ outp) {   // PBUF ? Pbuf : ABfinal
    const int dw = blockIdx.x * 32 + (threadIdx.x >> 6) * 8;
    const int kt0 = blockIdx.y * (NT / KS);
    const int lane = threadIdx.x & 63;   // m

    float accA[8] = {};
    float accB[8] = {};

#pragma unroll 2
    for (int t = kt0; t < kt0 + NT / KS; ++t) {
        const float aw = w1T[(size_t)t * 64 + lane];
        const float ae = e1T[(size_t)t * 64 + lane];
        const float4 x0 = *(const float4*)&Xp[(size_t)t * DP + dw];
        const float4 x1 = *(const float4*)&Xp[(size_t)t * DP + dw + 4];
        const float4 j0 = *(const float4*)&Jp[(size_t)t * DP + dw];
        const float4 j1 = *(const float4*)&Jp[(size_t)t * DP + dw + 4];
        accA[0] = fmaf(aw, x0.x, accA[0]);
        accA[1] = fmaf(aw, x0.y, accA[1]);
        accA[2] = fmaf(aw, x0.z, accA[2]);
        accA[3] = fmaf(aw, x0.w, accA[3]);
        accA[4] = fmaf(aw, x1.x, accA[4]);
        accA[5] = fmaf(aw, x1.y, accA[5]);
        accA[6] = fmaf(aw, x1.z, accA[6]);
        accA[7] = fmaf(aw, x1.w, accA[7]);
        accB[0] = fmaf(ae, j0.x, accB[0]);
        accB[1] = fmaf(ae, j0.y, accB[1]);
        accB[2] = fmaf(ae, j0.z, accB[2]);
        accB[3] = fmaf(ae, j0.w, accB[3]);
        accB[4] = fmaf(ae, j1.x, accB[4]);
        accB[5] = fmaf(ae, j1.y, accB[5]);
        accB[6] = fmaf(ae, j1.z, accB[6]);
        accB[7] = fmaf(ae, j1.w, accB[7]);
    }

    const size_t oA = (size_t)lane * DP + dw;
    const size_t oB = (size_t)NM * DP + oA;
    if (PBUF) {
        float* p = outp + (size_t)blockIdx.y * (2u * NM * DP);
        *(float4*)&p[oA]     = make_float4(accA[0], accA[1], accA[2], accA[3]);
        *(float4*)&p[oA + 4] = make_float4(accA[4], accA[5], accA[6], accA[7]);
        *(float4*)&p[oB]     = make_float4(accB[0], accB[1], accB[2], accB[3]);
        *(float4*)&p[oB + 4] = make_float4(accB[4], accB[5], accB[6], accB[7]);
    } else {
#pragma unroll
        for (int i = 0; i < 8; ++i) {
            atomicAdd(&outp[oA + i], accA[i]);
            atomicAdd(&outp[oB + i], accB[i]);
        }
    }
}

// grid 112 x 256: AB[o] = sum_ks Pbuf[ks][o]  (o < 2*64*224 = 28672)
__global__ void k_reduce(const float* __restrict__ P, float* __restrict__ AB) {
    const int o = blockIdx.x * 256 + threadIdx.x;
    float s0 = 0.0f, s1 = 0.0f, s2 = 0.0f, s3 = 0.0f;
    for (int k = 0; k < KS; k += 4) {
        s0 += P[(size_t)k * 28672 + o];
        s1 += P[(size_t)(k + 1) * 28672 + o];
        s2 += P[(size_t)(k + 2) * 28672 + o];
        s3 += P[(size_t)(k + 3) * 28672 + o];
    }
    AB[o] = (s0 + s1) + (s2 + s3);
}

// grid 64 (m) x 256: expand_tril + force contraction + Es
__global__ void k_final(const float* __restrict__ Rs, const float* __restrict__ qxsT,
                        const float* __restrict__ AB, const float* __restrict__ EsAcc,
                        const float* __restrict__ Wacc, float* __restrict__ out) {
    int m = blockIdx.x, tid = threadIdx.x;
    __shared__ float R[NA * 3];
    __shared__ float Ff[NA][NA];
    if (tid < NA * 3) R[tid] = Rs[m * NA * 3 + tid];
    if (tid < NA) Ff[tid][tid] = 0.0f;
    __syncthreads();
    if (tid < ND) {
        int i, j; d_to_ij(tid, i, j);
        float dx = R[i * 3] - R[j * 3];
        float dy = R[i * 3 + 1] - R[j * 3 + 1];
        float dz = R[i * 3 + 2] - R[j * 3 + 2];
        float dist2 = dx * dx + dy * dy + dz * dz;
        float fsx = qxsT[tid * NM + m] * Wacc[m]
                  - AB[(size_t)m * DP + tid]
                  - AB[(size_t)NM * DP + (size_t)m * DP + tid];
        float f = fsx / (dist2 * sqrtf(dist2));
        Ff[i][j] = f;
        Ff[j][i] = f;
    }
    __syncthreads();
    if (tid < NA * 3) {
        int a = tid / 3, c = tid % 3;
        float s = 0.0f;
        for (int b = 0; b < NA; ++b) {
            if (b == a) continue;
            s += Ff[a][b] * (R[a * 3 + c] - R[b * 3 + c]);
        }
        out[NM + m * NA * 3 + tid] = s;
    }
    if (tid == 0) out[m] = EsAcc[m] / QC;
}

extern "C" void kernel_launch(void* const* d_in, const int* in_sizes, int n_in,
                              void* d_out, int out_size, void* d_ws, size_t ws_size,
                              hipStream_t stream) {
    const float* Rs = (const float*)d_in[0];
    const float* xs_train = (const float*)d_in[1];
    const float* Jx_alphas = (const float*)d_in[2];
    float* out = (float*)d_out;
    float* ws = (float*)d_ws;

    float* Xp   = ws + O_XP;
    float* Jp   = ws + O_JP;
    float* w1T  = ws + O_W1;
    float* e1T  = ws + O_E1;
    float* qxsT = ws + O_QXST;
    float* nt   = ws + O_NT;
    float* cJ   = ws + O_CJ;
    float* nx   = ws + O_NX;
    float* EsAcc = ws + O_ES;
    float* Wacc  = ws + O_WA;
    float* ABf   = ws + O_AB;
    float* Pbuf  = ws + O_PB;

    const bool use_pbuf = ws_size >= (size_t)END_PB * sizeof(float);

    k_zero<<<(NZERO + 255) / 256, 256, 0, stream>>>(EsAcc, NZERO);
    k_geom<<<NM, 256, 0, stream>>>(Rs, qxsT, nx);
    k_pad<<<2 * NT * DP / 256, 256, 0, stream>>>(xs_train, Jx_alphas, Xp, Jp);
    k_rowstats<<<NT / 4, 256, 0, stream>>>(xs_train, Jx_alphas, nt, cJ);
    k_stage1<<<NT / 32, 256, 0, stream>>>(qxsT, Xp, Jp, nt, cJ, nx, w1T, e1T, EsAcc, Wacc);
    if (use_pbuf) {
        k_stage2<true><<<dim3(7, KS), 256, 0, stream>>>(w1T, e1T, Xp, Jp, Pbuf);
        k_reduce<<<112, 256, 0, stream>>>(Pbuf, ABf);
    } else {
        k_stage2<false><<<dim3(7, KS), 256, 0, stream>>>(w1T, e1T, Xp, Jp, ABf);
    }
    k_final<<<NM, 256, 0, stream>>>(Rs, qxsT, ABf, EsAcc, Wacc, out);
}

// Round 4
// 168.586 us; speedup vs baseline: 1.2486x; 1.0676x over previous
//
#include <hip/hip_runtime.h>
#include <math.h>

#define NA   21
#define NM   64
#define ND   210
#define DP   224          // padded descriptor row (d 210..223 zero)
#define DG   56           // 4-wide d-groups covering 0..223 (tail zero)
#define NT   8192
#define KS   128          // stage2 K-splits (64 t each)
#define KT   (NT / KS)    // 64

#define QC 0.22360679774997896f   // sqrt(5)/10
#define KE 0.016666666666666666f  // 5/(3*sig^2)

// ---- workspace layout (float offsets); ws proven >= 38 MB (round-1 pbuf ran) ----
#define O_XP   0u                  // [NT][DP]          1835008
#define O_JP   1835008u            // [NT][DP]          1835008
#define O_W1   3670016u            // [NT][64]          524288
#define O_E1   4194304u            // [NT][64]          524288
#define O_QG   4718592u            // qxsG [56][64][4]  14336
#define O_NTT  4732928u            // [NT]
#define O_CJ   4741120u            // [NT]
#define O_NX   4749312u            // [64]
#define O_ES   4749376u            // [64]
#define O_WA   4749440u            // [64]
#define O_AB   4749504u            // [2][64][DP]       28672
#define O_PB   4778176u            // [KS][2][64][DP]   3670016
#define END_PB 8448192u            // 33.8 MB
#define NZERO  (64 + 64 + 28672)   // ES+WA+AB contiguous

__device__ __forceinline__ void d_to_ij(int d, int& i, int& j) {
    int ii = (int)((1.0f + sqrtf(1.0f + 8.0f * (float)d)) * 0.5f);
    while (ii * (ii - 1) / 2 > d) --ii;
    while ((ii + 1) * ii / 2 <= d) ++ii;
    i = ii;
    j = d - ii * (ii - 1) / 2;
}

__global__ void k_zero(float* __restrict__ p, int n) {
    int i = blockIdx.x * 256 + threadIdx.x;
    if (i < n) p[i] = 0.0f;
}

// grid 64 (m) x 256: qxsG[(d>>2)][m][d&3] = q/dist(pair d), d 210..223 zero; nx[m]
__global__ void k_geom(const float* __restrict__ Rs, float* __restrict__ qxsG,
                       float* __restrict__ nx) {
    int m = blockIdx.x, tid = threadIdx.x;
    __shared__ float R[NA * 3];
    __shared__ float red[256];
    if (tid < NA * 3) R[tid] = Rs[m * NA * 3 + tid];
    __syncthreads();
    float local = 0.0f;
    if (tid < DP) {
        float v = 0.0f;
        if (tid < ND) {
            int i, j; d_to_ij(tid, i, j);
            float dx = R[i * 3] - R[j * 3];
            float dy = R[i * 3 + 1] - R[j * 3 + 1];
            float dz = R[i * 3 + 2] - R[j * 3 + 2];
            v = QC / sqrtf(dx * dx + dy * dy + dz * dz);
        }
        qxsG[(tid >> 2) * 256 + m * 4 + (tid & 3)] = v;
        local = v * v;
    }
    red[tid] = local;
    __syncthreads();
    for (int s = 128; s > 0; s >>= 1) {
        if (tid < s) red[tid] += red[tid + s];
        __syncthreads();
    }
    if (tid == 0) nx[m] = red[0];
}

// grid 3584 x 256: one float4 of padded output per thread
__global__ void k_pad(const float* __restrict__ xs, const float* __restrict__ Jx,
                      float* __restrict__ Xp, float* __restrict__ Jp) {
    int idx = blockIdx.x * 256 + threadIdx.x;   // < 2*NT*56
    int arr = idx / (NT * 56);
    int r = idx - arr * (NT * 56);
    int t = r / 56, c = r - t * 56;
    int d = c * 4;
    const float* p = (arr ? Jx : xs) + (size_t)t * ND + d;
    float sc = arr ? 1.0f : QC;
    float4 v = make_float4(0.f, 0.f, 0.f, 0.f);
    if (d + 3 < ND) {
        v.x = sc * p[0]; v.y = sc * p[1]; v.z = sc * p[2]; v.w = sc * p[3];
    } else {
        if (d < ND)     v.x = sc * p[0];
        if (d + 1 < ND) v.y = sc * p[1];
        if (d + 2 < ND) v.z = sc * p[2];
    }
    *(float4*)&(arr ? Jp : Xp)[(size_t)t * DP + d] = v;
}

// grid 2048 x 256 (wave per t): nt[t] = ||q xt||^2, cJ[t] = (q xt).Jx
__global__ void k_rowstats(const float* __restrict__ xs, const float* __restrict__ Jx,
                           float* __restrict__ nt, float* __restrict__ cJ) {
    int t = blockIdx.x * 4 + (threadIdx.x >> 6);
    int lane = threadIdx.x & 63;
    const float* xr = xs + (size_t)t * ND;
    const float* jr = Jx + (size_t)t * ND;
    float sn = 0.0f, sc = 0.0f;
    for (int c = lane; c < ND; c += 64) {
        float x = xr[c], j = jr[c];
        sn = fmaf(x, x, sn);
        sc = fmaf(x, j, sc);
    }
#pragma unroll
    for (int off = 32; off > 0; off >>= 1) {
        sn += __shfl_xor(sn, off);
        sc += __shfl_xor(sc, off);
    }
    if (lane == 0) {
        nt[t] = QC * QC * sn;
        cJ[t] = QC * sc;
    }
}

// Stage 1: grid 512 (t-strips of 16) x 256. lane=m, wave=4t. A panel in LDS
// ([g][m][4] -> one ds_read_b128/group). Depth-4 ring prefetch of B float4s.
__global__ __launch_bounds__(256, 2) void k_stage1(
    const float* __restrict__ qxsG, const float* __restrict__ Xp,
    const float* __restrict__ Jp, const float* __restrict__ nt,
    const float* __restrict__ cJ, const float* __restrict__ nx,
    float* __restrict__ w1T, float* __restrict__ e1T,
    float* __restrict__ EsAcc, float* __restrict__ Wacc) {
    const int tid = threadIdx.x;
    const int lane = tid & 63;          // m
    const int w = tid >> 6;
    const int tw = blockIdx.x * 16 + w * 4;
    __shared__ float A[DG * 256];       // 57344 B
    __shared__ float redE[4][64];
    __shared__ float redW[4][64];

    for (int i = tid; i < DG * 64; i += 256)
        ((float4*)A)[i] = ((const float4*)qxsG)[i];
    __syncthreads();

    const float* rowX[4];
    const float* rowJ[4];
#pragma unroll
    for (int j = 0; j < 4; ++j) {
        rowX[j] = Xp + (size_t)(tw + j) * DP;
        rowJ[j] = Jp + (size_t)(tw + j) * DP;
    }

    float c1[4] = {};
    float c2[4] = {};
    float4 bX[4][4], bJ[4][4];          // [slot][t]
#pragma unroll
    for (int p = 0; p < 4; ++p)
#pragma unroll
        for (int j = 0; j < 4; ++j) {
            bX[p][j] = *(const float4*)&rowX[j][p * 4];
            bJ[p][j] = *(const float4*)&rowJ[j][p * 4];
        }

#pragma unroll 4
    for (int g = 0; g < DG; ++g) {
        const int s = g & 3;
        const float4 a = *(const float4*)&A[g * 256 + lane * 4];
#pragma unroll
        for (int j = 0; j < 4; ++j) {
            const float4 x = bX[s][j];
            const float4 y = bJ[s][j];
            c1[j] = fmaf(a.x, x.x, fmaf(a.y, x.y, fmaf(a.z, x.z, fmaf(a.w, x.w, c1[j]))));
            c2[j] = fmaf(a.x, y.x, fmaf(a.y, y.y, fmaf(a.z, y.z, fmaf(a.w, y.w, c2[j]))));
        }
        const int gn = (g + 4 < DG) ? g + 4 : DG - 1;   // clamped redundant tail loads
#pragma unroll
        for (int j = 0; j < 4; ++j) {
            bX[s][j] = *(const float4*)&rowX[j][gn * 4];
            bJ[s][j] = *(const float4*)&rowJ[j][gn * 4];
        }
    }

    const float nxm = nx[lane];
    float es = 0.0f, wsum = 0.0f;
#pragma unroll
    for (int j = 0; j < 4; ++j) {
        const int t = tw + j;
        float sq = fmaxf(nxm - 2.0f * c1[j] + nt[t], 0.0f);
        float xd = sqrtf(sq);
        float e = KE * expf(-xd);
        float dotv = c2[j] - cJ[t];
        float wv = e * dotv;
        float ev = e * (1.0f + xd);
        w1T[(size_t)t * 64 + lane] = wv;     // coalesced
        e1T[(size_t)t * 64 + lane] = ev;
        es += ev * dotv;
        wsum += wv;
    }
    redE[w][lane] = es;
    redW[w][lane] = wsum;
    __syncthreads();
    if (tid < 64) {
        atomicAdd(&EsAcc[tid], redE[0][tid] + redE[1][tid] + redE[2][tid] + redE[3][tid]);
        atomicAdd(&Wacc[tid], redW[0][tid] + redW[1][tid] + redW[2][tid] + redW[3][tid]);
    }
}

// Stage 2: grid (7 d-tiles of 32, KS) x 256. lane=m, wave=8d, K-chunk 64 t.
// Depth-4 ring prefetch (6 loads/t in flight x4). No extra QC (Xp pre-scaled).
template <bool PBUF>
__global__ __launch_bounds__(256, 2) void k_stage2(
    const float* __restrict__ w1T, const float* __restrict__ e1T,
    const float* __restrict__ Xp, const float* __restrict__ Jp,
    float* __restrict__ outp) {   // PBUF ? Pbuf : ABfinal
    const int dw = blockIdx.x * 32 + (threadIdx.x >> 6) * 8;
    const int kt0 = blockIdx.y * KT;
    const int lane = threadIdx.x & 63;   // m

    float accA[8] = {};
    float accB[8] = {};
    float bw[4], be[4];
    float4 bx0[4], bx1[4], bj0[4], bj1[4];

#pragma unroll
    for (int p = 0; p < 4; ++p) {
        const int t = kt0 + p;
        bw[p] = w1T[(size_t)t * 64 + lane];
        be[p] = e1T[(size_t)t * 64 + lane];
        bx0[p] = *(const float4*)&Xp[(size_t)t * DP + dw];
        bx1[p] = *(const float4*)&Xp[(size_t)t * DP + dw + 4];
        bj0[p] = *(const float4*)&Jp[(size_t)t * DP + dw];
        bj1[p] = *(const float4*)&Jp[(size_t)t * DP + dw + 4];
    }

#pragma unroll 4
    for (int i = 0; i < KT; ++i) {
        const int s = i & 3;
        const float aw = bw[s], ae = be[s];
        const float4 x0 = bx0[s], x1 = bx1[s], j0 = bj0[s], j1 = bj1[s];
        accA[0] = fmaf(aw, x0.x, accA[0]);
        accA[1] = fmaf(aw, x0.y, accA[1]);
        accA[2] = fmaf(aw, x0.z, accA[2]);
        accA[3] = fmaf(aw, x0.w, accA[3]);
        accA[4] = fmaf(aw, x1.x, accA[4]);
        accA[5] = fmaf(aw, x1.y, accA[5]);
        accA[6] = fmaf(aw, x1.z, accA[6]);
        accA[7] = fmaf(aw, x1.w, accA[7]);
        accB[0] = fmaf(ae, j0.x, accB[0]);
        accB[1] = fmaf(ae, j0.y, accB[1]);
        accB[2] = fmaf(ae, j0.z, accB[2]);
        accB[3] = fmaf(ae, j0.w, accB[3]);
        accB[4] = fmaf(ae, j1.x, accB[4]);
        accB[5] = fmaf(ae, j1.y, accB[5]);
        accB[6] = fmaf(ae, j1.z, accB[6]);
        accB[7] = fmaf(ae, j1.w, accB[7]);
        const int tn = kt0 + ((i + 4 < KT) ? i + 4 : KT - 1);  // clamped tail
        bw[s] = w1T[(size_t)tn * 64 + lane];
        be[s] = e1T[(size_t)tn * 64 + lane];
        bx0[s] = *(const float4*)&Xp[(size_t)tn * DP + dw];
        bx1[s] = *(const float4*)&Xp[(size_t)tn * DP + dw + 4];
        bj0[s] = *(const float4*)&Jp[(size_t)tn * DP + dw];
        bj1[s] = *(const float4*)&Jp[(size_t)tn * DP + dw + 4];
    }

    const size_t oA = (size_t)lane * DP + dw;
    const size_t oB = (size_t)NM * DP + oA;
    if (PBUF) {
        float* p = outp + (size_t)blockIdx.y * (2u * NM * DP);
        *(float4*)&p[oA]     = make_float4(accA[0], accA[1], accA[2], accA[3]);
        *(float4*)&p[oA + 4] = make_float4(accA[4], accA[5], accA[6], accA[7]);
        *(float4*)&p[oB]     = make_float4(accB[0], accB[1], accB[2], accB[3]);
        *(float4*)&p[oB + 4] = make_float4(accB[4], accB[5], accB[6], accB[7]);
    } else {
#pragma unroll
        for (int i = 0; i < 8; ++i) {
            atomicAdd(&outp[oA + i], accA[i]);
            atomicAdd(&outp[oB + i], accB[i]);
        }
    }
}

// grid (112, 8) x 256: AB[o] += sum over 16 k-slices of Pbuf[k][o]
__global__ void k_reduce(const float* __restrict__ P, float* __restrict__ AB) {
    const int o = blockIdx.x * 256 + threadIdx.x;
    const int k0 = blockIdx.y * 16;
    float s0 = 0.0f, s1 = 0.0f, s2 = 0.0f, s3 = 0.0f;
#pragma unroll
    for (int k = 0; k < 16; k += 4) {
        s0 += P[(size_t)(k0 + k) * 28672 + o];
        s1 += P[(size_t)(k0 + k + 1) * 28672 + o];
        s2 += P[(size_t)(k0 + k + 2) * 28672 + o];
        s3 += P[(size_t)(k0 + k + 3) * 28672 + o];
    }
    atomicAdd(&AB[o], (s0 + s1) + (s2 + s3));
}

// grid 64 (m) x 256: expand_tril + force contraction + Es
__global__ void k_final(const float* __restrict__ Rs, const float* __restrict__ qxsG,
                        const float* __restrict__ AB, const float* __restrict__ EsAcc,
                        const float* __restrict__ Wacc, float* __restrict__ out) {
    int m = blockIdx.x, tid = threadIdx.x;
    __shared__ float R[NA * 3];
    __shared__ float Ff[NA][NA];
    if (tid < NA * 3) R[tid] = Rs[m * NA * 3 + tid];
    if (tid < NA) Ff[tid][tid] = 0.0f;
    __syncthreads();
    if (tid < ND) {
        int i, j; d_to_ij(tid, i, j);
        float dx = R[i * 3] - R[j * 3];
        float dy = R[i * 3 + 1] - R[j * 3 + 1];
        float dz = R[i * 3 + 2] - R[j * 3 + 2];
        float dist2 = dx * dx + dy * dy + dz * dz;
        float fsx = qxsG[(tid >> 2) * 256 + m * 4 + (tid & 3)] * Wacc[m]
                  - AB[(size_t)m * DP + tid]
                  - AB[(size_t)NM * DP + (size_t)m * DP + tid];
        float f = fsx / (dist2 * sqrtf(dist2));
        Ff[i][j] = f;
        Ff[j][i] = f;
    }
    __syncthreads();
    if (tid < NA * 3) {
        int a = tid / 3, c = tid % 3;
        float s = 0.0f;
        for (int b = 0; b < NA; ++b) {
            if (b == a) continue;
            s += Ff[a][b] * (R[a * 3 + c] - R[b * 3 + c]);
        }
        out[NM + m * NA * 3 + tid] = s;
    }
    if (tid == 0) out[m] = EsAcc[m] / QC;
}

extern "C" void kernel_launch(void* const* d_in, const int* in_sizes, int n_in,
                              void* d_out, int out_size, void* d_ws, size_t ws_size,
                              hipStream_t stream) {
    const float* Rs = (const float*)d_in[0];
    const float* xs_train = (const float*)d_in[1];
    const float* Jx_alphas = (const float*)d_in[2];
    float* out = (float*)d_out;
    float* ws = (float*)d_ws;

    float* Xp   = ws + O_XP;
    float* Jp   = ws + O_JP;
    float* w1T  = ws + O_W1;
    float* e1T  = ws + O_E1;
    float* qxsG = ws + O_QG;
    float* nt   = ws + O_NTT;
    float* cJ   = ws + O_CJ;
    float* nx   = ws + O_NX;
    float* EsAcc = ws + O_ES;
    float* Wacc  = ws + O_WA;
    float* ABf   = ws + O_AB;
    float* Pbuf  = ws + O_PB;

    const bool use_pbuf = ws_size >= (size_t)END_PB * sizeof(float);

    k_zero<<<(NZERO + 255) / 256, 256, 0, stream>>>(EsAcc, NZERO);
    k_geom<<<NM, 256, 0, stream>>>(Rs, qxsG, nx);
    k_pad<<<2 * NT * 56 / 256, 256, 0, stream>>>(xs_train, Jx_alphas, Xp, Jp);
    k_rowstats<<<NT / 4, 256, 0, stream>>>(xs_train, Jx_alphas, nt, cJ);
    k_stage1<<<NT / 16, 256, 0, stream>>>(qxsG, Xp, Jp, nt, cJ, nx, w1T, e1T, EsAcc, Wacc);
    if (use_pbuf) {
        k_stage2<true><<<dim3(7, KS), 256, 0, stream>>>(w1T, e1T, Xp, Jp, Pbuf);
        k_reduce<<<dim3(112, 8), 256, 0, stream>>>(Pbuf, ABf);
    } else {
        k_stage2<false><<<dim3(7, KS), 256, 0, stream>>>(w1T, e1T, Xp, Jp, ABf);
    }
    k_final<<<NM, 256, 0, stream>>>(Rs, qxsG, ABf, EsAcc, Wacc, out);
}

// Round 5
// 121.834 us; speedup vs baseline: 1.7277x; 1.3837x over previous
//
#include <hip/hip_runtime.h>
#include <math.h>

#define NA   21
#define NM   64
#define ND   210
#define DP   224          // padded descriptor row (d 210..223 zero)
#define DG   56           // 4-wide d-groups
#define NT   8192
#define KS   128          // stage2 K-splits (64 t each)
#define KT   64

#define QC 0.22360679774997896f   // sqrt(5)/10
#define KE 0.016666666666666666f  // 5/(3*sig^2)

// ---- workspace layout (float offsets); pbuf path proven to run (round 3/4) ----
#define O_XP   0u                  // [NT][DP]          1835008
#define O_JP   1835008u            // [NT][DP]          1835008
#define O_W1   3670016u            // [NT][64]          524288
#define O_E1   4194304u            // [NT][64]          524288
#define O_QG   4718592u            // qxsG [56][64][4]  14336
#define O_NTT  4732928u            // [NT]
#define O_CJ   4741120u            // [NT]
#define O_NX   4749312u            // [64]
#define O_ES   4749376u            // [64]
#define O_WA   4749440u            // [64]
#define O_AB   4749504u            // [2][64][DP]       28672
#define O_PB   4778176u            // [KS][2][64][DP]   3670016
#define END_PB 8448192u            // 33.8 MB
#define NZERO  (64 + 64 + 28672)   // ES+WA+AB contiguous

__device__ __forceinline__ void d_to_ij(int d, int& i, int& j) {
    int ii = (int)((1.0f + sqrtf(1.0f + 8.0f * (float)d)) * 0.5f);
    while (ii * (ii - 1) / 2 > d) --ii;
    while ((ii + 1) * ii / 2 <= d) ++ii;
    i = ii;
    j = d - ii * (ii - 1) / 2;
}

// Fused prep: blocks [0,3584) pad, [3584,3648) geom, [3648,5696) rowstats,
// [5696,5809) zero accumulators. All roles independent.
__global__ __launch_bounds__(256) void k_prep(
    const float* __restrict__ Rs, const float* __restrict__ xs,
    const float* __restrict__ Jx, float* __restrict__ Xp, float* __restrict__ Jp,
    float* __restrict__ qxsG, float* __restrict__ nx, float* __restrict__ nt,
    float* __restrict__ cJ, float* __restrict__ zbase) {
    const int b = blockIdx.x, tid = threadIdx.x;
    __shared__ float R[NA * 3];
    __shared__ float red[256];
    if (b < 3584) {                       // ---- pad: one float4 per thread
        int idx = b * 256 + tid;          // < 2*NT*56
        int arr = idx / (NT * 56);
        int r = idx - arr * (NT * 56);
        int t = r / 56, c = r - t * 56;
        int d = c * 4;
        const float* p = (arr ? Jx : xs) + (size_t)t * ND + d;
        float sc = arr ? 1.0f : QC;
        float4 v = make_float4(0.f, 0.f, 0.f, 0.f);
        if (d + 3 < ND) {
            v.x = sc * p[0]; v.y = sc * p[1]; v.z = sc * p[2]; v.w = sc * p[3];
        } else {
            if (d < ND)     v.x = sc * p[0];
            if (d + 1 < ND) v.y = sc * p[1];
            if (d + 2 < ND) v.z = sc * p[2];
        }
        *(float4*)&(arr ? Jp : Xp)[(size_t)t * DP + d] = v;
    } else if (b < 3648) {                // ---- geom: m = b-3584
        int m = b - 3584;
        if (tid < NA * 3) R[tid] = Rs[m * NA * 3 + tid];
        __syncthreads();
        float local = 0.0f;
        if (tid < DP) {
            float v = 0.0f;
            if (tid < ND) {
                int i, j; d_to_ij(tid, i, j);
                float dx = R[i * 3] - R[j * 3];
                float dy = R[i * 3 + 1] - R[j * 3 + 1];
                float dz = R[i * 3 + 2] - R[j * 3 + 2];
                v = QC / sqrtf(dx * dx + dy * dy + dz * dz);
            }
            qxsG[(tid >> 2) * 256 + m * 4 + (tid & 3)] = v;
            local = v * v;
        }
        red[tid] = local;
        __syncthreads();
        for (int s = 128; s > 0; s >>= 1) {
            if (tid < s) red[tid] += red[tid + s];
            __syncthreads();
        }
        if (tid == 0) nx[m] = red[0];
    } else if (b < 5696) {                // ---- rowstats: wave per t
        int t = (b - 3648) * 4 + (tid >> 6);
        int lane = tid & 63;
        const float* xr = xs + (size_t)t * ND;
        const float* jr = Jx + (size_t)t * ND;
        float sn = 0.0f, sc = 0.0f;
        for (int c = lane; c < ND; c += 64) {
            float x = xr[c], j = jr[c];
            sn = fmaf(x, x, sn);
            sc = fmaf(x, j, sc);
        }
#pragma unroll
        for (int off = 32; off > 0; off >>= 1) {
            sn += __shfl_xor(sn, off);
            sc += __shfl_xor(sc, off);
        }
        if (lane == 0) {
            nt[t] = QC * QC * sn;
            cJ[t] = QC * sc;
        }
    } else {                              // ---- zero ES/WA/AB
        int i = (b - 5696) * 256 + tid;
        if (i < NZERO) zbase[i] = 0.0f;
    }
}

// Stage 1: grid 512 (t-strips of 16). lane=m, wave=4t. A panel (56KB) in LDS;
// B staged through LDS in 7 double-buffered chunks of 32 d (full-width loads).
__global__ __launch_bounds__(256) void k_stage1(
    const float* __restrict__ qxsG, const float* __restrict__ Xp,
    const float* __restrict__ Jp, const float* __restrict__ nt,
    const float* __restrict__ cJ, const float* __restrict__ nx,
    float* __restrict__ w1T, float* __restrict__ e1T,
    float* __restrict__ EsAcc, float* __restrict__ Wacc) {
    const int tid = threadIdx.x;
    const int lane = tid & 63;          // m
    const int w = tid >> 6;
    const int t0 = blockIdx.x * 16;
    const int tw = w * 4;               // wave's t within strip

    __shared__ float A[DG * 256];       // [56][64][4]  57344 B
    __shared__ float SB[2][2][16][32];  // [buf][arr][t][d]  16384 B
    __shared__ float redE[4][64];
    __shared__ float redW[4][64];

    // A-panel: full-width loads + ds_write (one-time)
#pragma unroll
    for (int k = 0; k < 14; ++k) {
        const int i = k * 256 + tid;    // float4 index < 3584
        ((float4*)A)[i] = ((const float4*)qxsG)[i];
    }

    // staging role: thread -> one float4 of the (X|J) chunk
    const int arr = tid >> 7;           // 0: X, 1: J
    const int f = tid & 127;            // f4 within chunk
    const int st = f >> 3, sdc = (f & 7) * 4;
    const float* sbase = (arr ? Jp : Xp) + (size_t)(t0 + st) * DP + sdc;
    float4 pre = *(const float4*)&sbase[0];       // chunk 0

    __syncthreads();                    // A-panel visible (chunk 0 still in regs)

    float c1[4] = {}, c2[4] = {};
#pragma unroll 1
    for (int c = 0; c < 7; ++c) {
        const int buf = c & 1;
        *(float4*)&SB[buf][arr][st][sdc] = pre;
        __syncthreads();                              // chunk c ready
        if (c < 6) pre = *(const float4*)&sbase[(c + 1) * 32];  // issue early
#pragma unroll
        for (int g = 0; g < 8; ++g) {
            const float4 a = *(const float4*)&A[(c * 8 + g) * 256 + lane * 4];
#pragma unroll
            for (int j = 0; j < 4; ++j) {
                const float4 x = *(const float4*)&SB[buf][0][tw + j][g * 4];
                const float4 y = *(const float4*)&SB[buf][1][tw + j][g * 4];
                c1[j] = fmaf(a.x, x.x, fmaf(a.y, x.y, fmaf(a.z, x.z, fmaf(a.w, x.w, c1[j]))));
                c2[j] = fmaf(a.x, y.x, fmaf(a.y, y.y, fmaf(a.z, y.z, fmaf(a.w, y.w, c2[j]))));
            }
        }
    }

    const float nxm = nx[lane];
    float es = 0.0f, wsum = 0.0f;
#pragma unroll
    for (int j = 0; j < 4; ++j) {
        const int t = t0 + tw + j;
        float sq = fmaxf(nxm - 2.0f * c1[j] + nt[t], 0.0f);
        float xd = sqrtf(sq);
        float e = KE * expf(-xd);
        float dotv = c2[j] - cJ[t];
        float wv = e * dotv;
        float ev = e * (1.0f + xd);
        w1T[(size_t)t * 64 + lane] = wv;     // coalesced 256 B
        e1T[(size_t)t * 64 + lane] = ev;
        es += ev * dotv;
        wsum += wv;
    }
    redE[w][lane] = es;
    redW[w][lane] = wsum;
    __syncthreads();
    if (tid < 64) {
        atomicAdd(&EsAcc[tid], redE[0][tid] + redE[1][tid] + redE[2][tid] + redE[3][tid]);
        atomicAdd(&Wacc[tid], redW[0][tid] + redW[1][tid] + redW[2][tid] + redW[3][tid]);
    }
}

// Stage 2: grid (7 d-tiles of 32, KS k-splits of 64 t). lane=m, wave=8d.
// Xp/Jp staged through LDS (4 dbuf chunks of 16 t); w1/e1 direct coalesced.
template <bool PBUF>
__global__ __launch_bounds__(256) void k_stage2(
    const float* __restrict__ w1T, const float* __restrict__ e1T,
    const float* __restrict__ Xp, const float* __restrict__ Jp,
    float* __restrict__ outp) {   // PBUF ? Pbuf : ABfinal
    const int dt0 = blockIdx.x * 32;
    const int kt0 = blockIdx.y * KT;
    const int tid = threadIdx.x;
    const int lane = tid & 63;          // m
    const int w = tid >> 6;
    const int dw = w * 8;               // d within tile

    __shared__ float SB[2][2][16][32];  // [buf][arr][t][d]  16384 B

    const int arr = tid >> 7;
    const int f = tid & 127;
    const int st = f >> 3, sdc = (f & 7) * 4;
    const float* sbase = (arr ? Jp : Xp) + (size_t)(kt0 + st) * DP + dt0 + sdc;
    float4 pre = *(const float4*)&sbase[0];

    float accA[8] = {}, accB[8] = {};
#pragma unroll 1
    for (int c = 0; c < 4; ++c) {
        const int buf = c & 1;
        *(float4*)&SB[buf][arr][st][sdc] = pre;
        __syncthreads();
        if (c < 3) pre = *(const float4*)&sbase[(size_t)(c + 1) * 16 * DP];
        const int tb = kt0 + c * 16;
#pragma unroll
        for (int tt = 0; tt < 16; ++tt) {
            const float aw = w1T[(size_t)(tb + tt) * 64 + lane];
            const float ae = e1T[(size_t)(tb + tt) * 64 + lane];
            const float4 x0 = *(const float4*)&SB[buf][0][tt][dw];
            const float4 x1 = *(const float4*)&SB[buf][0][tt][dw + 4];
            const float4 j0 = *(const float4*)&SB[buf][1][tt][dw];
            const float4 j1 = *(const float4*)&SB[buf][1][tt][dw + 4];
            accA[0] = fmaf(aw, x0.x, accA[0]);
            accA[1] = fmaf(aw, x0.y, accA[1]);
            accA[2] = fmaf(aw, x0.z, accA[2]);
            accA[3] = fmaf(aw, x0.w, accA[3]);
            accA[4] = fmaf(aw, x1.x, accA[4]);
            accA[5] = fmaf(aw, x1.y, accA[5]);
            accA[6] = fmaf(aw, x1.z, accA[6]);
            accA[7] = fmaf(aw, x1.w, accA[7]);
            accB[0] = fmaf(ae, j0.x, accB[0]);
            accB[1] = fmaf(ae, j0.y, accB[1]);
            accB[2] = fmaf(ae, j0.z, accB[2]);
            accB[3] = fmaf(ae, j0.w, accB[3]);
            accB[4] = fmaf(ae, j1.x, accB[4]);
            accB[5] = fmaf(ae, j1.y, accB[5]);
            accB[6] = fmaf(ae, j1.z, accB[6]);
            accB[7] = fmaf(ae, j1.w, accB[7]);
        }
    }

    const size_t oA = (size_t)lane * DP + dt0 + dw;
    const size_t oB = (size_t)NM * DP + oA;
    if (PBUF) {
        float* p = outp + (size_t)blockIdx.y * (2u * NM * DP);
        *(float4*)&p[oA]     = make_float4(accA[0], accA[1], accA[2], accA[3]);
        *(float4*)&p[oA + 4] = make_float4(accA[4], accA[5], accA[6], accA[7]);
        *(float4*)&p[oB]     = make_float4(accB[0], accB[1], accB[2], accB[3]);
        *(float4*)&p[oB + 4] = make_float4(accB[4], accB[5], accB[6], accB[7]);
    } else {
#pragma unroll
        for (int i = 0; i < 8; ++i) {
            atomicAdd(&outp[oA + i], accA[i]);
            atomicAdd(&outp[oB + i], accB[i]);
        }
    }
}

// grid (112, 8) x 256: AB[o] += sum over 16 k-slices of Pbuf[k][o]
__global__ void k_reduce(const float* __restrict__ P, float* __restrict__ AB) {
    const int o = blockIdx.x * 256 + threadIdx.x;
    const int k0 = blockIdx.y * 16;
    float s0 = 0.0f, s1 = 0.0f, s2 = 0.0f, s3 = 0.0f;
#pragma unroll
    for (int k = 0; k < 16; k += 4) {
        s0 += P[(size_t)(k0 + k) * 28672 + o];
        s1 += P[(size_t)(k0 + k + 1) * 28672 + o];
        s2 += P[(size_t)(k0 + k + 2) * 28672 + o];
        s3 += P[(size_t)(k0 + k + 3) * 28672 + o];
    }
    atomicAdd(&AB[o], (s0 + s1) + (s2 + s3));
}

// grid 64 (m) x 256: expand_tril + force contraction + Es
__global__ void k_final(const float* __restrict__ Rs, const float* __restrict__ qxsG,
                        const float* __restrict__ AB, const float* __restrict__ EsAcc,
                        const float* __restrict__ Wacc, float* __restrict__ out) {
    int m = blockIdx.x, tid = threadIdx.x;
    __shared__ float R[NA * 3];
    __shared__ float Ff[NA][NA];
    if (tid < NA * 3) R[tid] = Rs[m * NA * 3 + tid];
    if (tid < NA) Ff[tid][tid] = 0.0f;
    __syncthreads();
    if (tid < ND) {
        int i, j; d_to_ij(tid, i, j);
        float dx = R[i * 3] - R[j * 3];
        float dy = R[i * 3 + 1] - R[j * 3 + 1];
        float dz = R[i * 3 + 2] - R[j * 3 + 2];
        float dist2 = dx * dx + dy * dy + dz * dz;
        float fsx = qxsG[(tid >> 2) * 256 + m * 4 + (tid & 3)] * Wacc[m]
                  - AB[(size_t)m * DP + tid]
                  - AB[(size_t)NM * DP + (size_t)m * DP + tid];
        float f = fsx / (dist2 * sqrtf(dist2));
        Ff[i][j] = f;
        Ff[j][i] = f;
    }
    __syncthreads();
    if (tid < NA * 3) {
        int a = tid / 3, c = tid % 3;
        float s = 0.0f;
        for (int b = 0; b < NA; ++b) {
            if (b == a) continue;
            s += Ff[a][b] * (R[a * 3 + c] - R[b * 3 + c]);
        }
        out[NM + m * NA * 3 + tid] = s;
    }
    if (tid == 0) out[m] = EsAcc[m] / QC;
}

extern "C" void kernel_launch(void* const* d_in, const int* in_sizes, int n_in,
                              void* d_out, int out_size, void* d_ws, size_t ws_size,
                              hipStream_t stream) {
    const float* Rs = (const float*)d_in[0];
    const float* xs_train = (const float*)d_in[1];
    const float* Jx_alphas = (const float*)d_in[2];
    float* out = (float*)d_out;
    float* ws = (float*)d_ws;

    float* Xp   = ws + O_XP;
    float* Jp   = ws + O_JP;
    float* w1T  = ws + O_W1;
    float* e1T  = ws + O_E1;
    float* qxsG = ws + O_QG;
    float* nt   = ws + O_NTT;
    float* cJ   = ws + O_CJ;
    float* nx   = ws + O_NX;
    float* EsAcc = ws + O_ES;
    float* Wacc  = ws + O_WA;
    float* ABf   = ws + O_AB;
    float* Pbuf  = ws + O_PB;

    const bool use_pbuf = ws_size >= (size_t)END_PB * sizeof(float);

    k_prep<<<5809, 256, 0, stream>>>(Rs, xs_train, Jx_alphas, Xp, Jp, qxsG, nx, nt, cJ, EsAcc);
    k_stage1<<<NT / 16, 256, 0, stream>>>(qxsG, Xp, Jp, nt, cJ, nx, w1T, e1T, EsAcc, Wacc);
    if (use_pbuf) {
        k_stage2<true><<<dim3(7, KS), 256, 0, stream>>>(w1T, e1T, Xp, Jp, Pbuf);
        k_reduce<<<dim3(112, 8), 256, 0, stream>>>(Pbuf, ABf);
    } else {
        k_stage2<false><<<dim3(7, KS), 256, 0, stream>>>(w1T, e1T, Xp, Jp, ABf);
    }
    k_final<<<NM, 256, 0, stream>>>(Rs, qxsG, ABf, EsAcc, Wacc, out);
}